// Round 1
// baseline (132.551 us; speedup 1.0000x reference)
//
#include <hip/hip_runtime.h>
#include <math.h>

#define NB 32
#define NA 3
#define NH 52
#define NW 52
#define NC 80
#define G  20
#define CH 85               // 5 + NC
#define PLANE (NH*NW)       // 2704
#define CELLS (NB*NA*NH*NW) // 259584

__constant__ float c_aw[NA] = {1.25f, 2.0f, 4.125f};   // ANCHORS_PX / SCALE (SCALE=8)
__constant__ float c_ah[NA] = {1.625f, 3.75f, 2.875f};

__device__ __forceinline__ float sigmoidf_(float x) { return 1.0f / (1.0f + expf(-x)); }
__device__ __forceinline__ float softplusf_(float x) {
    return fmaxf(x, 0.0f) + log1pf(expf(-fabsf(x)));
}

// acc layout (floats): 0=conf_sum 1=xc_sum 2=yc_sum 3=w_sum 4=h_sum 5=cls_sum 6=nCorrect
__global__ void init_acc(float* acc) {
    int i = threadIdx.x;
    if (i < 7) acc[i] = 0.0f;
}

// One thread per cell (b,a,h,w). Baseline contributions:
//  - conf: (ignore?0:0.5) * softplus(conf)   [tconf=0 baseline]
//  - warm_up coords: (sig(x)-0.5)^2, (sig(y)-0.5)^2, w^2, h^2
__global__ void cell_kernel(const float* __restrict__ out,
                            const float* __restrict__ bboxes,
                            const int*   __restrict__ warm_up,
                            float* __restrict__ acc)
{
    int idx = blockIdx.x * blockDim.x + threadIdx.x;
    float s_conf = 0.f, s_xc = 0.f, s_yc = 0.f, s_w = 0.f, s_h = 0.f;
    if (idx < CELLS) {
        int w_i = idx % NW;
        int h_i = (idx / NW) % NH;
        int a_i = (idx / PLANE) % NA;
        int b_i = idx / (NA * PLANE);

        const float* base = out + ((size_t)b_i * NA * CH + (size_t)a_i * CH) * PLANE
                                + h_i * NW + w_i;
        float o0 = base[0];
        float o1 = base[PLANE];
        float o2 = base[2 * PLANE];
        float o3 = base[3 * PLANE];
        float o4 = base[4 * PLANE];

        float xc = sigmoidf_(o0), yc = sigmoidf_(o1);
        float pw = expf(o2) * c_aw[a_i];
        float ph = expf(o3) * c_ah[a_i];
        float px = xc + (float)w_i, py = yc + (float)h_i;
        float px0 = px - 0.5f * pw, py0 = py - 0.5f * ph;
        float px1 = px + 0.5f * pw, py1 = py + 0.5f * ph;
        float ap = (px1 - px0) * (py1 - py0);

        const float* gb = bboxes + (size_t)b_i * G * 4;
        float miou = 0.f;
        #pragma unroll
        for (int g = 0; g < G; ++g) {
            float gx = gb[g*4+0] * 0.125f, gy = gb[g*4+1] * 0.125f;
            float gw = gb[g*4+2] * 0.125f, gh = gb[g*4+3] * 0.125f;
            float gx0 = gx - 0.5f*gw, gy0 = gy - 0.5f*gh;
            float gx1 = gx + 0.5f*gw, gy1 = gy + 0.5f*gh;
            float ag = (gx1 - gx0) * (gy1 - gy0);
            float iw = fmaxf(fminf(px1, gx1) - fmaxf(px0, gx0), 0.f);
            float ih = fmaxf(fminf(py1, gy1) - fmaxf(py0, gy0), 0.f);
            float inter = iw * ih;
            float iou = inter / (ap + ag - inter + 1e-10f);
            miou = fmaxf(miou, iou);
        }
        bool ignore = miou > 0.5f;
        float confw = ignore ? 0.0f : 0.5f;
        s_conf = confw * softplusf_(o4);

        if (*warm_up != 0) {
            s_xc = (xc - 0.5f) * (xc - 0.5f);
            s_yc = (yc - 0.5f) * (yc - 0.5f);
            s_w  = o2 * o2;
            s_h  = o3 * o3;
        }
    }
    // per-wave reduce (wave64), one atomic per wave per sum
    #pragma unroll
    for (int off = 32; off > 0; off >>= 1) {
        s_conf += __shfl_down(s_conf, off);
        s_xc   += __shfl_down(s_xc,   off);
        s_yc   += __shfl_down(s_yc,   off);
        s_w    += __shfl_down(s_w,    off);
        s_h    += __shfl_down(s_h,    off);
    }
    if ((threadIdx.x & 63) == 0) {
        atomicAdd(acc + 0, s_conf);
        if (*warm_up != 0) {
            atomicAdd(acc + 1, s_xc);
            atomicAdd(acc + 2, s_yc);
            atomicAdd(acc + 3, s_w);
            atomicAdd(acc + 4, s_h);
        }
    }
}

// One thread per (b,g) pair: nCorrect + scatter corrections (last-wins dedupe).
__global__ void pair_kernel(const float* __restrict__ out,
                            const float* __restrict__ bboxes,
                            const int*   __restrict__ labels,
                            const int*   __restrict__ anchor_idx,
                            const int*   __restrict__ warm_up,
                            float* __restrict__ acc)
{
    int p = blockIdx.x * blockDim.x + threadIdx.x;
    if (p >= NB * G) return;
    int b = p / G, g = p % G;

    const float* gb = bboxes + (size_t)b * G * 4;
    float gx = gb[g*4+0] * 0.125f, gy = gb[g*4+1] * 0.125f;
    float gw = gb[g*4+2] * 0.125f, gh = gb[g*4+3] * 0.125f;
    int a = anchor_idx[p];
    int gi = min(max((int)gx, 0), NW - 1);
    int gj = min(max((int)gy, 0), NH - 1);

    const float* base = out + ((size_t)b * NA * CH + (size_t)a * CH) * PLANE
                            + gj * NW + gi;
    float o0 = base[0];
    float o1 = base[PLANE];
    float o2 = base[2 * PLANE];
    float o3 = base[3 * PLANE];
    float o4 = base[4 * PLANE];

    float xc = sigmoidf_(o0), yc = sigmoidf_(o1);
    float pw = expf(o2) * c_aw[a];
    float ph = expf(o3) * c_ah[a];
    float px = xc + (float)gi, py = yc + (float)gj;
    float px0 = px - 0.5f*pw, py0 = py - 0.5f*ph;
    float px1 = px + 0.5f*pw, py1 = py + 0.5f*ph;
    float ap = (px1 - px0) * (py1 - py0);

    // nCorrect: 1-on-1 IoU with own gt (counted for ALL pairs, no dedupe)
    {
        float gx0 = gx - 0.5f*gw, gy0 = gy - 0.5f*gh;
        float gx1 = gx + 0.5f*gw, gy1 = gy + 0.5f*gh;
        float ag = (gx1 - gx0) * (gy1 - gy0);
        float iw = fmaxf(fminf(px1, gx1) - fmaxf(px0, gx0), 0.f);
        float ih = fmaxf(fminf(py1, gy1) - fmaxf(py0, gy0), 0.f);
        float inter = iw * ih;
        float iou = inter / (ap + ag - inter + 1e-10f);
        if (iou > 0.5f) atomicAdd(acc + 6, 1.0f);
    }

    // last-wins dedupe: inactive if a later pair in same batch hits same (a,gj,gi)
    for (int q = g + 1; q < G; ++q) {
        int aq = anchor_idx[b * G + q];
        if (aq != a) continue;
        float qx = gb[q*4+0] * 0.125f, qy = gb[q*4+1] * 0.125f;
        int qi = min(max((int)qx, 0), NW - 1);
        int qj = min(max((int)qy, 0), NH - 1);
        if (qi == gi && qj == gj) return;
    }

    // recompute ignore for this cell (identical math to cell_kernel)
    float miou = 0.f;
    for (int q = 0; q < G; ++q) {
        float qx = gb[q*4+0] * 0.125f, qy = gb[q*4+1] * 0.125f;
        float qw = gb[q*4+2] * 0.125f, qh = gb[q*4+3] * 0.125f;
        float qx0 = qx - 0.5f*qw, qy0 = qy - 0.5f*qh;
        float qx1 = qx + 0.5f*qw, qy1 = qy + 0.5f*qh;
        float ag = (qx1 - qx0) * (qy1 - qy0);
        float iw = fmaxf(fminf(px1, qx1) - fmaxf(px0, qx0), 0.f);
        float ih = fmaxf(fminf(py1, qy1) - fmaxf(py0, qy0), 0.f);
        float inter = iw * ih;
        float iou = inter / (ap + ag - inter + 1e-10f);
        miou = fmaxf(miou, iou);
    }
    bool ignore = miou > 0.5f;

    // conf correction: remove baseline noobj term, add obj term (weight 5, tconf=1)
    float sp4 = softplusf_(o4);
    float base_conf = (ignore ? 0.0f : 0.5f) * sp4;
    atomicAdd(acc + 0, 5.0f * (sp4 - o4) - base_conf);

    // coord corrections
    float txc = gx - (float)gi;
    float tyc = gy - (float)gj;
    float tw  = logf(gw / c_aw[a]);
    float th  = logf(gh / c_ah[a]);
    bool wu = (*warm_up != 0);
    float bx = wu ? (xc - 0.5f) * (xc - 0.5f) : 0.f;
    float by = wu ? (yc - 0.5f) * (yc - 0.5f) : 0.f;
    float bw = wu ? o2 * o2 : 0.f;
    float bh = wu ? o3 * o3 : 0.f;
    atomicAdd(acc + 1, (xc - txc) * (xc - txc) - bx);
    atomicAdd(acc + 2, (yc - tyc) * (yc - tyc) - by);
    atomicAdd(acc + 3, (o2 - tw) * (o2 - tw) - bw);
    atomicAdd(acc + 4, (o3 - th) * (o3 - th) - bh);

    // class bce: sum_c softplus(x_c) - x_label
    int lab = labels[p];
    const float* cbase = out + ((size_t)b * NA * CH + (size_t)a * CH + 5) * PLANE
                             + gj * NW + gi;
    float s = 0.f;
    for (int c = 0; c < NC; ++c) s += softplusf_(cbase[(size_t)c * PLANE]);
    s -= cbase[(size_t)lab * PLANE];
    atomicAdd(acc + 5, s);
}

__global__ void finalize_kernel(const float* __restrict__ acc, float* __restrict__ o)
{
    const float invB = 1.0f / (float)NB;
    float lxc = acc[1] * 0.5f * invB;
    float lyc = acc[2] * 0.5f * invB;
    float lw  = acc[3] * 0.5f * invB;
    float lh  = acc[4] * 0.5f * invB;
    float lconf = acc[0] * invB;
    float lcls  = acc[5] * invB;
    float loss = lxc + lyc + lw + lh + lconf + lcls;
    o[0] = loss;
    o[1] = (float)(NB * G);   // nGT
    o[2] = acc[6];            // nCorrect
    o[3] = lxc;
    o[4] = lyc;
    o[5] = lw;
    o[6] = lh;
    o[7] = lconf;
    o[8] = lcls;
}

extern "C" void kernel_launch(void* const* d_in, const int* in_sizes, int n_in,
                              void* d_out, int out_size, void* d_ws, size_t ws_size,
                              hipStream_t stream)
{
    const float* output     = (const float*)d_in[0];
    const float* bboxes     = (const float*)d_in[1];
    const int*   labels     = (const int*)d_in[2];
    const int*   anchor_idx = (const int*)d_in[3];
    const int*   warm_up    = (const int*)d_in[4];
    float* acc  = (float*)d_ws;
    float* outp = (float*)d_out;

    init_acc<<<1, 64, 0, stream>>>(acc);
    cell_kernel<<<(CELLS + 255) / 256, 256, 0, stream>>>(output, bboxes, warm_up, acc);
    pair_kernel<<<(NB * G + 255) / 256, 256, 0, stream>>>(output, bboxes, labels,
                                                          anchor_idx, warm_up, acc);
    finalize_kernel<<<1, 1, 0, stream>>>(acc, outp);
}

// Round 2
// 122.009 us; speedup vs baseline: 1.0864x; 1.0864x over previous
//
#include <hip/hip_runtime.h>
#include <math.h>

#define NB 32
#define NA 3
#define NH 52
#define NW 52
#define NC 80
#define G  20
#define CH 85               // 5 + NC
#define PLANE (NH*NW)       // 2704
#define APLANE (NA*PLANE)   // 8112 cells per batch

__constant__ float c_aw[NA] = {1.25f, 2.0f, 4.125f};   // ANCHORS_PX / SCALE (SCALE=8)
__constant__ float c_ah[NA] = {1.625f, 3.75f, 2.875f};

__device__ __forceinline__ float sigmoidf_(float x) { return 1.0f / (1.0f + expf(-x)); }
__device__ __forceinline__ float softplusf_(float x) {
    return fmaxf(x, 0.0f) + log1pf(expf(-fabsf(x)));
}

// acc layout (floats): 0=conf_sum 1=xc_sum 2=yc_sum 3=w_sum 4=h_sum 5=cls_sum 6=nCorrect

// One thread per cell within batch blockIdx.y. GT corners staged in LDS.
__global__ void cell_kernel(const float* __restrict__ out,
                            const float* __restrict__ bboxes,
                            const int*   __restrict__ warm_up,
                            float* __restrict__ acc)
{
    __shared__ float s_x0[G], s_y0[G], s_x1[G], s_y1[G], s_ag[G];
    int b_i = blockIdx.y;
    int t = threadIdx.x;
    if (t < G) {
        const float* gb = bboxes + ((size_t)b_i * G + t) * 4;
        float gx = gb[0] * 0.125f, gy = gb[1] * 0.125f;
        float gw = gb[2] * 0.125f, gh = gb[3] * 0.125f;
        s_x0[t] = gx - 0.5f * gw;
        s_y0[t] = gy - 0.5f * gh;
        s_x1[t] = gx + 0.5f * gw;
        s_y1[t] = gy + 0.5f * gh;
        s_ag[t] = gw * gh;
    }
    __syncthreads();

    int idx = blockIdx.x * blockDim.x + t;   // cell within (NA, NH, NW)
    float s_conf = 0.f, s_xc = 0.f, s_yc = 0.f, s_w = 0.f, s_h = 0.f;
    bool wu = (*warm_up != 0);
    if (idx < APLANE) {
        int w_i = idx % NW;
        int h_i = (idx / NW) % NH;
        int a_i = idx / PLANE;

        const float* base = out + ((size_t)b_i * NA * CH + (size_t)a_i * CH) * PLANE
                                + h_i * NW + w_i;
        float o0 = base[0];
        float o1 = base[PLANE];
        float o2 = base[2 * PLANE];
        float o3 = base[3 * PLANE];
        float o4 = base[4 * PLANE];

        float xc = sigmoidf_(o0), yc = sigmoidf_(o1);
        float pw = expf(o2) * c_aw[a_i];
        float ph = expf(o3) * c_ah[a_i];
        float px = xc + (float)w_i, py = yc + (float)h_i;
        float px0 = px - 0.5f * pw, py0 = py - 0.5f * ph;
        float px1 = px + 0.5f * pw, py1 = py + 0.5f * ph;
        float ap = (px1 - px0) * (py1 - py0);

        float miou = 0.f;
        #pragma unroll
        for (int g = 0; g < G; ++g) {
            float iw = fmaxf(fminf(px1, s_x1[g]) - fmaxf(px0, s_x0[g]), 0.f);
            float ih = fmaxf(fminf(py1, s_y1[g]) - fmaxf(py0, s_y0[g]), 0.f);
            float inter = iw * ih;
            float iou = inter / (ap + s_ag[g] - inter + 1e-10f);
            miou = fmaxf(miou, iou);
        }
        bool ignore = miou > 0.5f;
        s_conf = (ignore ? 0.0f : 0.5f) * softplusf_(o4);

        if (wu) {
            s_xc = (xc - 0.5f) * (xc - 0.5f);
            s_yc = (yc - 0.5f) * (yc - 0.5f);
            s_w  = o2 * o2;
            s_h  = o3 * o3;
        }
    }
    // per-wave reduce (wave64), one atomic per wave per sum
    #pragma unroll
    for (int off = 32; off > 0; off >>= 1) {
        s_conf += __shfl_down(s_conf, off);
        if (wu) {
            s_xc += __shfl_down(s_xc, off);
            s_yc += __shfl_down(s_yc, off);
            s_w  += __shfl_down(s_w,  off);
            s_h  += __shfl_down(s_h,  off);
        }
    }
    if ((threadIdx.x & 63) == 0) {
        atomicAdd(acc + 0, s_conf);
        if (wu) {
            atomicAdd(acc + 1, s_xc);
            atomicAdd(acc + 2, s_yc);
            atomicAdd(acc + 3, s_w);
            atomicAdd(acc + 4, s_h);
        }
    }
}

// One WAVE per (b,g) pair: lanes parallelize the 80 class channels;
// scalar work done redundantly by all lanes (broadcast loads); atomics by lane 0.
__global__ void pair_kernel(const float* __restrict__ out,
                            const float* __restrict__ bboxes,
                            const int*   __restrict__ labels,
                            const int*   __restrict__ anchor_idx,
                            const int*   __restrict__ warm_up,
                            float* __restrict__ acc)
{
    int p = (blockIdx.x * blockDim.x + threadIdx.x) >> 6;  // pair index
    int lane = threadIdx.x & 63;
    if (p >= NB * G) return;
    int b = p / G, g = p % G;

    const float* gb = bboxes + (size_t)b * G * 4;
    float gx = gb[g*4+0] * 0.125f, gy = gb[g*4+1] * 0.125f;
    float gw = gb[g*4+2] * 0.125f, gh = gb[g*4+3] * 0.125f;
    int a = anchor_idx[p];
    int gi = min(max((int)gx, 0), NW - 1);
    int gj = min(max((int)gy, 0), NH - 1);

    const float* cell = out + ((size_t)b * NA * CH + (size_t)a * CH) * PLANE
                            + gj * NW + gi;

    // ---- class BCE: lanes load channels in parallel (issue early, reduce later)
    int lab = labels[p];
    float v1 = cell[(size_t)(5 + lane) * PLANE];            // ch 5+lane (lane 0..63)
    float v2 = (lane < NC - 64) ? cell[(size_t)(5 + 64 + lane) * PLANE] : 0.f;
    float s = softplusf_(v1) - ((lane == lab) ? v1 : 0.f);
    if (lane < NC - 64)
        s += softplusf_(v2) - (((64 + lane) == lab) ? v2 : 0.f);

    // ---- scalar loads: all lanes same address -> broadcast
    float o0 = cell[0];
    float o1 = cell[PLANE];
    float o2 = cell[2 * PLANE];
    float o3 = cell[3 * PLANE];
    float o4 = cell[4 * PLANE];

    float xc = sigmoidf_(o0), yc = sigmoidf_(o1);
    float pw = expf(o2) * c_aw[a];
    float ph = expf(o3) * c_ah[a];
    float px = xc + (float)gi, py = yc + (float)gj;
    float px0 = px - 0.5f*pw, py0 = py - 0.5f*ph;
    float px1 = px + 0.5f*pw, py1 = py + 0.5f*ph;
    float ap = (px1 - px0) * (py1 - py0);

    // nCorrect: 1-on-1 IoU with own gt (all pairs, no dedupe)
    {
        float gx0 = gx - 0.5f*gw, gy0 = gy - 0.5f*gh;
        float gx1 = gx + 0.5f*gw, gy1 = gy + 0.5f*gh;
        float ag = gw * gh;
        float iw = fmaxf(fminf(px1, gx1) - fmaxf(px0, gx0), 0.f);
        float ih = fmaxf(fminf(py1, gy1) - fmaxf(py0, gy0), 0.f);
        float inter = iw * ih;
        float iou = inter / (ap + ag - inter + 1e-10f);
        if (lane == 0 && iou > 0.5f) atomicAdd(acc + 6, 1.0f);
    }

    // last-wins dedupe: inactive if a later pair in same batch hits same (a,gj,gi)
    // (wave-uniform: all lanes compute identically)
    for (int q = g + 1; q < G; ++q) {
        int aq = anchor_idx[b * G + q];
        if (aq != a) continue;
        float qx = gb[q*4+0] * 0.125f, qy = gb[q*4+1] * 0.125f;
        int qi = min(max((int)qx, 0), NW - 1);
        int qj = min(max((int)qy, 0), NH - 1);
        if (qi == gi && qj == gj) return;
    }

    // recompute ignore for this cell (same math as cell_kernel)
    float miou = 0.f;
    for (int q = 0; q < G; ++q) {
        float qx = gb[q*4+0] * 0.125f, qy = gb[q*4+1] * 0.125f;
        float qw = gb[q*4+2] * 0.125f, qh = gb[q*4+3] * 0.125f;
        float qx0 = qx - 0.5f*qw, qy0 = qy - 0.5f*qh;
        float qx1 = qx + 0.5f*qw, qy1 = qy + 0.5f*qh;
        float ag = qw * qh;
        float iw = fmaxf(fminf(px1, qx1) - fmaxf(px0, qx0), 0.f);
        float ih = fmaxf(fminf(py1, qy1) - fmaxf(py0, qy0), 0.f);
        float inter = iw * ih;
        float iou = inter / (ap + ag - inter + 1e-10f);
        miou = fmaxf(miou, iou);
    }
    bool ignore = miou > 0.5f;

    // reduce class sum across the wave
    #pragma unroll
    for (int off = 32; off > 0; off >>= 1) s += __shfl_down(s, off);

    if (lane == 0) {
        // conf correction: remove baseline noobj term, add obj term (w=5, tconf=1)
        float sp4 = softplusf_(o4);
        float base_conf = (ignore ? 0.0f : 0.5f) * sp4;
        atomicAdd(acc + 0, 5.0f * (sp4 - o4) - base_conf);

        // coord corrections
        float txc = gx - (float)gi;
        float tyc = gy - (float)gj;
        float tw  = logf(gw / c_aw[a]);
        float th  = logf(gh / c_ah[a]);
        bool wu = (*warm_up != 0);
        float bx = wu ? (xc - 0.5f) * (xc - 0.5f) : 0.f;
        float by = wu ? (yc - 0.5f) * (yc - 0.5f) : 0.f;
        float bw = wu ? o2 * o2 : 0.f;
        float bh = wu ? o3 * o3 : 0.f;
        atomicAdd(acc + 1, (xc - txc) * (xc - txc) - bx);
        atomicAdd(acc + 2, (yc - tyc) * (yc - tyc) - by);
        atomicAdd(acc + 3, (o2 - tw) * (o2 - tw) - bw);
        atomicAdd(acc + 4, (o3 - th) * (o3 - th) - bh);
        atomicAdd(acc + 5, s);
    }
}

__global__ void finalize_kernel(const float* __restrict__ acc, float* __restrict__ o)
{
    const float invB = 1.0f / (float)NB;
    float lxc = acc[1] * 0.5f * invB;
    float lyc = acc[2] * 0.5f * invB;
    float lw  = acc[3] * 0.5f * invB;
    float lh  = acc[4] * 0.5f * invB;
    float lconf = acc[0] * invB;
    float lcls  = acc[5] * invB;
    float loss = lxc + lyc + lw + lh + lconf + lcls;
    o[0] = loss;
    o[1] = (float)(NB * G);   // nGT
    o[2] = acc[6];            // nCorrect
    o[3] = lxc;
    o[4] = lyc;
    o[5] = lw;
    o[6] = lh;
    o[7] = lconf;
    o[8] = lcls;
}

extern "C" void kernel_launch(void* const* d_in, const int* in_sizes, int n_in,
                              void* d_out, int out_size, void* d_ws, size_t ws_size,
                              hipStream_t stream)
{
    const float* output     = (const float*)d_in[0];
    const float* bboxes     = (const float*)d_in[1];
    const int*   labels     = (const int*)d_in[2];
    const int*   anchor_idx = (const int*)d_in[3];
    const int*   warm_up    = (const int*)d_in[4];
    float* acc  = (float*)d_ws;
    float* outp = (float*)d_out;

    hipMemsetAsync(acc, 0, 7 * sizeof(float), stream);

    dim3 cgrid((APLANE + 255) / 256, NB);
    cell_kernel<<<cgrid, 256, 0, stream>>>(output, bboxes, warm_up, acc);

    int pair_blocks = (NB * G * 64 + 255) / 256;   // 160 blocks, 1 wave per pair
    pair_kernel<<<pair_blocks, 256, 0, stream>>>(output, bboxes, labels,
                                                 anchor_idx, warm_up, acc);
    finalize_kernel<<<1, 1, 0, stream>>>(acc, outp);
}

// Round 3
// 20.915 us; speedup vs baseline: 6.3375x; 5.8335x over previous
//
#include <hip/hip_runtime.h>
#include <math.h>

#define NB 32
#define NA 3
#define NH 52
#define NW 52
#define NC 80
#define G  20
#define CH 85               // 5 + NC
#define PLANE (NH*NW)       // 2704
#define APLANE (NA*PLANE)   // 8112 cells per batch
#define QUADS_PER_B (APLANE/4)   // 2028 4-cell groups per batch
#define CELL_BLOCKS 256     // 8 blocks/batch * 32 batches
#define PAIR_BLOCKS 160     // 640 pairs, 4 waves/block
#define NPAIR (NB*G)        // 640

// ws layout (floats):
//   [0 .. 256*8)          cell partials: conf,xc,yc,w,h,0,0,0 per block
//   [2048 .. 2048+640*8)  pair partials: conf,xc,yc,w,h,cls,ncorr,0 per pair
#define WS_PAIR_OFF 2048

__constant__ float c_aw[NA] = {1.25f, 2.0f, 4.125f};   // ANCHORS_PX / SCALE (SCALE=8)
__constant__ float c_ah[NA] = {1.625f, 3.75f, 2.875f};

__device__ __forceinline__ float sigmoidf_(float x) { return 1.0f / (1.0f + expf(-x)); }
__device__ __forceinline__ float softplusf_(float x) {
    return fmaxf(x, 0.0f) + log1pf(expf(-fabsf(x)));
}

__global__ void __launch_bounds__(256)
main_kernel(const float* __restrict__ out,
            const float* __restrict__ bboxes,
            const int*   __restrict__ labels,
            const int*   __restrict__ anchor_idx,
            const int*   __restrict__ warm_up,
            float* __restrict__ ws)
{
    __shared__ float s_x0[G], s_y0[G], s_x1[G], s_y1[G], s_ag[G];
    __shared__ float red[4][5];
    int bid = blockIdx.x;
    int t = threadIdx.x;

    if (bid < CELL_BLOCKS) {
        // ================= cell path: 4 cells/thread via float4 =================
        int b_i = bid >> 3;
        int bx  = bid & 7;
        if (t < G) {
            const float* gb = bboxes + ((size_t)b_i * G + t) * 4;
            float gx = gb[0] * 0.125f, gy = gb[1] * 0.125f;
            float gw = gb[2] * 0.125f, gh = gb[3] * 0.125f;
            s_x0[t] = gx - 0.5f * gw;
            s_y0[t] = gy - 0.5f * gh;
            s_x1[t] = gx + 0.5f * gw;
            s_y1[t] = gy + 0.5f * gh;
            s_ag[t] = gw * gh;
        }
        __syncthreads();

        bool wu = (*warm_up != 0);
        float sc = 0.f, sx = 0.f, sy = 0.f, sw = 0.f, sh = 0.f;
        int idx4 = bx * 256 + t;
        if (idx4 < QUADS_PER_B) {
            int cell0 = idx4 * 4;
            int a_i = cell0 / PLANE;
            int rem = cell0 - a_i * PLANE;
            int h_i = rem / NW;
            int w0  = rem - h_i * NW;      // multiple of 4, row-aligned

            const float* base = out + ((size_t)b_i * NA * CH + (size_t)a_i * CH) * PLANE
                                    + h_i * NW + w0;
            float4 v0 = *(const float4*)(base);
            float4 v1 = *(const float4*)(base + PLANE);
            float4 v2 = *(const float4*)(base + 2 * PLANE);
            float4 v3 = *(const float4*)(base + 3 * PLANE);
            float4 v4 = *(const float4*)(base + 4 * PLANE);
            float o0[4] = {v0.x, v0.y, v0.z, v0.w};
            float o1[4] = {v1.x, v1.y, v1.z, v1.w};
            float o2[4] = {v2.x, v2.y, v2.z, v2.w};
            float o3[4] = {v3.x, v3.y, v3.z, v3.w};
            float o4[4] = {v4.x, v4.y, v4.z, v4.w};

            float aw = c_aw[a_i], ah = c_ah[a_i];
            #pragma unroll
            for (int j = 0; j < 4; ++j) {
                float xc = sigmoidf_(o0[j]), yc = sigmoidf_(o1[j]);
                float pw = expf(o2[j]) * aw;
                float ph = expf(o3[j]) * ah;
                float px = xc + (float)(w0 + j), py = yc + (float)h_i;
                float px0 = px - 0.5f * pw, py0 = py - 0.5f * ph;
                float px1 = px + 0.5f * pw, py1 = py + 0.5f * ph;
                float ap = pw * ph;

                float miou = 0.f;
                #pragma unroll
                for (int g = 0; g < G; ++g) {
                    float iw = fmaxf(fminf(px1, s_x1[g]) - fmaxf(px0, s_x0[g]), 0.f);
                    float ih = fmaxf(fminf(py1, s_y1[g]) - fmaxf(py0, s_y0[g]), 0.f);
                    float inter = iw * ih;
                    float iou = inter / (ap + s_ag[g] - inter + 1e-10f);
                    miou = fmaxf(miou, iou);
                }
                bool ignore = miou > 0.5f;
                sc += (ignore ? 0.0f : 0.5f) * softplusf_(o4[j]);
                if (wu) {
                    sx += (xc - 0.5f) * (xc - 0.5f);
                    sy += (yc - 0.5f) * (yc - 0.5f);
                    sw += o2[j] * o2[j];
                    sh += o3[j] * o3[j];
                }
            }
        }
        // wave reduce, then LDS across the 4 waves, one plain store per block
        #pragma unroll
        for (int off = 32; off > 0; off >>= 1) {
            sc += __shfl_down(sc, off);
            sx += __shfl_down(sx, off);
            sy += __shfl_down(sy, off);
            sw += __shfl_down(sw, off);
            sh += __shfl_down(sh, off);
        }
        int lane = t & 63, wid = t >> 6;
        if (lane == 0) {
            red[wid][0] = sc; red[wid][1] = sx; red[wid][2] = sy;
            red[wid][3] = sw; red[wid][4] = sh;
        }
        __syncthreads();
        if (t == 0) {
            float r0 = 0.f, r1 = 0.f, r2 = 0.f, r3 = 0.f, r4 = 0.f;
            #pragma unroll
            for (int w = 0; w < 4; ++w) {
                r0 += red[w][0]; r1 += red[w][1]; r2 += red[w][2];
                r3 += red[w][3]; r4 += red[w][4];
            }
            float* dst = ws + (size_t)bid * 8;
            dst[0] = r0; dst[1] = r1; dst[2] = r2; dst[3] = r3; dst[4] = r4;
            dst[5] = 0.f; dst[6] = 0.f; dst[7] = 0.f;
        }
    } else {
        // ================= pair path: one wave per (b,g) pair =================
        int pb = bid - CELL_BLOCKS;
        int p = pb * 4 + (t >> 6);       // < 640 always
        int lane = t & 63;
        int b = p / G, g = p % G;

        const float* gb = bboxes + (size_t)b * G * 4;
        float gx = gb[g*4+0] * 0.125f, gy = gb[g*4+1] * 0.125f;
        float gw = gb[g*4+2] * 0.125f, gh = gb[g*4+3] * 0.125f;
        int a = anchor_idx[p];
        int gi = min(max((int)gx, 0), NW - 1);
        int gj = min(max((int)gy, 0), NH - 1);

        const float* cell = out + ((size_t)b * NA * CH + (size_t)a * CH) * PLANE
                                + gj * NW + gi;

        // class BCE loads in lane-parallel (issue early)
        int lab = labels[p];
        float v1 = cell[(size_t)(5 + lane) * PLANE];
        float v2 = (lane < NC - 64) ? cell[(size_t)(5 + 64 + lane) * PLANE] : 0.f;
        float s = softplusf_(v1) - ((lane == lab) ? v1 : 0.f);
        if (lane < NC - 64)
            s += softplusf_(v2) - (((64 + lane) == lab) ? v2 : 0.f);

        float o0 = cell[0];
        float o1 = cell[PLANE];
        float o2 = cell[2 * PLANE];
        float o3 = cell[3 * PLANE];
        float o4 = cell[4 * PLANE];

        float xc = sigmoidf_(o0), yc = sigmoidf_(o1);
        float pw = expf(o2) * c_aw[a];
        float ph = expf(o3) * c_ah[a];
        float px = xc + (float)gi, py = yc + (float)gj;
        float px0 = px - 0.5f*pw, py0 = py - 0.5f*ph;
        float px1 = px + 0.5f*pw, py1 = py + 0.5f*ph;
        float ap = pw * ph;

        // nCorrect: all pairs, no dedupe
        float ncorr;
        {
            float gx0 = gx - 0.5f*gw, gy0 = gy - 0.5f*gh;
            float gx1 = gx + 0.5f*gw, gy1 = gy + 0.5f*gh;
            float ag = gw * gh;
            float iw = fmaxf(fminf(px1, gx1) - fmaxf(px0, gx0), 0.f);
            float ih = fmaxf(fminf(py1, gy1) - fmaxf(py0, gy0), 0.f);
            float inter = iw * ih;
            float iou = inter / (ap + ag - inter + 1e-10f);
            ncorr = (iou > 0.5f) ? 1.0f : 0.0f;
        }

        // last-wins dedupe (wave-uniform)
        bool active = true;
        for (int q = g + 1; q < G; ++q) {
            int aq = anchor_idx[b * G + q];
            if (aq != a) continue;
            float qx = gb[q*4+0] * 0.125f, qy = gb[q*4+1] * 0.125f;
            int qi = min(max((int)qx, 0), NW - 1);
            int qj = min(max((int)qy, 0), NH - 1);
            if (qi == gi && qj == gj) { active = false; break; }
        }

        // recompute ignore for this cell (same math as cell path)
        float miou = 0.f;
        for (int q = 0; q < G; ++q) {
            float qx = gb[q*4+0] * 0.125f, qy = gb[q*4+1] * 0.125f;
            float qw = gb[q*4+2] * 0.125f, qh = gb[q*4+3] * 0.125f;
            float qx0 = qx - 0.5f*qw, qy0 = qy - 0.5f*qh;
            float qx1 = qx + 0.5f*qw, qy1 = qy + 0.5f*qh;
            float ag = qw * qh;
            float iw = fmaxf(fminf(px1, qx1) - fmaxf(px0, qx0), 0.f);
            float ih = fmaxf(fminf(py1, qy1) - fmaxf(py0, qy0), 0.f);
            float inter = iw * ih;
            float iou = inter / (ap + ag - inter + 1e-10f);
            miou = fmaxf(miou, iou);
        }
        bool ignore = miou > 0.5f;

        // reduce class sum across the wave (all lanes participate)
        #pragma unroll
        for (int off = 32; off > 0; off >>= 1) s += __shfl_down(s, off);

        if (lane == 0) {
            float dconf = 0.f, dxc = 0.f, dyc = 0.f, dw = 0.f, dh = 0.f, dcls = 0.f;
            if (active) {
                float sp4 = softplusf_(o4);
                float base_conf = (ignore ? 0.0f : 0.5f) * sp4;
                dconf = 5.0f * (sp4 - o4) - base_conf;

                float txc = gx - (float)gi;
                float tyc = gy - (float)gj;
                float tw  = logf(gw / c_aw[a]);
                float th  = logf(gh / c_ah[a]);
                bool wu = (*warm_up != 0);
                float bx = wu ? (xc - 0.5f) * (xc - 0.5f) : 0.f;
                float by = wu ? (yc - 0.5f) * (yc - 0.5f) : 0.f;
                float bw = wu ? o2 * o2 : 0.f;
                float bh = wu ? o3 * o3 : 0.f;
                dxc = (xc - txc) * (xc - txc) - bx;
                dyc = (yc - tyc) * (yc - tyc) - by;
                dw  = (o2 - tw) * (o2 - tw) - bw;
                dh  = (o3 - th) * (o3 - th) - bh;
                dcls = s;
            }
            float* dst = ws + WS_PAIR_OFF + (size_t)p * 8;
            dst[0] = dconf; dst[1] = dxc; dst[2] = dyc;
            dst[3] = dw;    dst[4] = dh;  dst[5] = dcls;
            dst[6] = ncorr; dst[7] = 0.f;
        }
    }
}

__global__ void __launch_bounds__(256)
finalize_kernel(const float* __restrict__ ws, float* __restrict__ o)
{
    __shared__ float red[4][7];
    int t = threadIdx.x;
    float a0=0,a1=0,a2=0,a3=0,a4=0,a5=0,a6=0;

    // cell partials: exactly 256 rows
    {
        const float* c = ws + (size_t)t * 8;
        a0 += c[0]; a1 += c[1]; a2 += c[2]; a3 += c[3]; a4 += c[4];
    }
    // pair partials: 640 rows
    for (int r = t; r < NPAIR; r += 256) {
        const float* pr = ws + WS_PAIR_OFF + (size_t)r * 8;
        a0 += pr[0]; a1 += pr[1]; a2 += pr[2]; a3 += pr[3];
        a4 += pr[4]; a5 += pr[5]; a6 += pr[6];
    }
    #pragma unroll
    for (int off = 32; off > 0; off >>= 1) {
        a0 += __shfl_down(a0, off);
        a1 += __shfl_down(a1, off);
        a2 += __shfl_down(a2, off);
        a3 += __shfl_down(a3, off);
        a4 += __shfl_down(a4, off);
        a5 += __shfl_down(a5, off);
        a6 += __shfl_down(a6, off);
    }
    int lane = t & 63, wid = t >> 6;
    if (lane == 0) {
        red[wid][0]=a0; red[wid][1]=a1; red[wid][2]=a2; red[wid][3]=a3;
        red[wid][4]=a4; red[wid][5]=a5; red[wid][6]=a6;
    }
    __syncthreads();
    if (t == 0) {
        float c0=0,c1=0,c2=0,c3=0,c4=0,c5=0,c6=0;
        #pragma unroll
        for (int w = 0; w < 4; ++w) {
            c0+=red[w][0]; c1+=red[w][1]; c2+=red[w][2]; c3+=red[w][3];
            c4+=red[w][4]; c5+=red[w][5]; c6+=red[w][6];
        }
        const float invB = 1.0f / (float)NB;
        float lxc = c1 * 0.5f * invB;
        float lyc = c2 * 0.5f * invB;
        float lw  = c3 * 0.5f * invB;
        float lh  = c4 * 0.5f * invB;
        float lconf = c0 * invB;
        float lcls  = c5 * invB;
        o[0] = lxc + lyc + lw + lh + lconf + lcls;
        o[1] = (float)(NB * G);   // nGT
        o[2] = c6;                // nCorrect
        o[3] = lxc;
        o[4] = lyc;
        o[5] = lw;
        o[6] = lh;
        o[7] = lconf;
        o[8] = lcls;
    }
}

extern "C" void kernel_launch(void* const* d_in, const int* in_sizes, int n_in,
                              void* d_out, int out_size, void* d_ws, size_t ws_size,
                              hipStream_t stream)
{
    const float* output     = (const float*)d_in[0];
    const float* bboxes     = (const float*)d_in[1];
    const int*   labels     = (const int*)d_in[2];
    const int*   anchor_idx = (const int*)d_in[3];
    const int*   warm_up    = (const int*)d_in[4];
    float* ws   = (float*)d_ws;
    float* outp = (float*)d_out;

    main_kernel<<<CELL_BLOCKS + PAIR_BLOCKS, 256, 0, stream>>>(
        output, bboxes, labels, anchor_idx, warm_up, ws);
    finalize_kernel<<<1, 256, 0, stream>>>(ws, outp);
}

// Round 4
// 15.690 us; speedup vs baseline: 8.4480x; 1.3330x over previous
//
#include <hip/hip_runtime.h>
#include <math.h>

#define NB 32
#define NA 3
#define NH 52
#define NW 52
#define NC 80
#define G  20
#define CH 85               // 5 + NC
#define PLANE (NH*NW)       // 2704
#define APLANE (NA*PLANE)   // 8112 cells per batch
#define QUADS_PER_B (APLANE/4)   // 2028 4-cell groups per batch
#define CELL_BLOCKS 256     // 8 blocks/batch * 32 batches
#define PAIR_BLOCKS 160     // 640 pairs, 4 waves/block
#define NPAIR (NB*G)        // 640
#define TOTAL_ROWS (CELL_BLOCKS + PAIR_BLOCKS)   // 416 rows of 8 floats in ws

__constant__ float c_aw[NA] = {1.25f, 2.0f, 4.125f};   // ANCHORS_PX / SCALE (SCALE=8)
__constant__ float c_ah[NA] = {1.625f, 3.75f, 2.875f};

__device__ __forceinline__ float rcp_(float x) { return __builtin_amdgcn_rcpf(x); }
__device__ __forceinline__ float sigmoidf_(float x) { return rcp_(1.0f + __expf(-x)); }
__device__ __forceinline__ float softplusf_(float x) {
    return fmaxf(x, 0.0f) + __logf(1.0f + __expf(-fabsf(x)));
}

// ws: 416 rows x 8 floats. rows [0,256): cell blocks; rows [256,416): pair blocks.
// fields: 0=conf 1=xc 2=yc 3=w 4=h 5=cls 6=ncorr 7=pad

__global__ void __launch_bounds__(256)
main_kernel(const float* __restrict__ out,
            const float* __restrict__ bboxes,
            const int*   __restrict__ labels,
            const int*   __restrict__ anchor_idx,
            const int*   __restrict__ warm_up,
            float* __restrict__ ws)
{
    __shared__ float s_x0[G], s_y0[G], s_x1[G], s_y1[G], s_ag[G];
    __shared__ float red[4][7];
    int bid = blockIdx.x;
    int t = threadIdx.x;
    int lane = t & 63, wid = t >> 6;

    if (bid < CELL_BLOCKS) {
        // ================= cell path: 4 cells/thread via float4 =================
        int b_i = bid >> 3;
        int bx  = bid & 7;
        if (t < G) {
            const float* gb = bboxes + ((size_t)b_i * G + t) * 4;
            float gx = gb[0] * 0.125f, gy = gb[1] * 0.125f;
            float gw = gb[2] * 0.125f, gh = gb[3] * 0.125f;
            s_x0[t] = gx - 0.5f * gw;
            s_y0[t] = gy - 0.5f * gh;
            s_x1[t] = gx + 0.5f * gw;
            s_y1[t] = gy + 0.5f * gh;
            s_ag[t] = gw * gh;
        }
        __syncthreads();

        bool wu = (*warm_up != 0);
        float sc = 0.f, sx = 0.f, sy = 0.f, sw = 0.f, sh = 0.f;
        int idx4 = bx * 256 + t;
        if (idx4 < QUADS_PER_B) {
            int cell0 = idx4 * 4;
            int a_i = cell0 / PLANE;
            int rem = cell0 - a_i * PLANE;
            int h_i = rem / NW;
            int w0  = rem - h_i * NW;      // multiple of 4, row-aligned

            const float* base = out + ((size_t)b_i * NA * CH + (size_t)a_i * CH) * PLANE
                                    + h_i * NW + w0;
            float4 v0 = *(const float4*)(base);
            float4 v1 = *(const float4*)(base + PLANE);
            float4 v2 = *(const float4*)(base + 2 * PLANE);
            float4 v3 = *(const float4*)(base + 3 * PLANE);
            float4 v4 = *(const float4*)(base + 4 * PLANE);
            float o0[4] = {v0.x, v0.y, v0.z, v0.w};
            float o1[4] = {v1.x, v1.y, v1.z, v1.w};
            float o2[4] = {v2.x, v2.y, v2.z, v2.w};
            float o3[4] = {v3.x, v3.y, v3.z, v3.w};
            float o4[4] = {v4.x, v4.y, v4.z, v4.w};

            float aw = c_aw[a_i], ah = c_ah[a_i];
            float px0[4], py0[4], px1[4], py1[4], ap[4], xc[4], yc[4], miou[4];
            #pragma unroll
            for (int j = 0; j < 4; ++j) {
                xc[j] = sigmoidf_(o0[j]);
                yc[j] = sigmoidf_(o1[j]);
                float pw = __expf(o2[j]) * aw;
                float ph = __expf(o3[j]) * ah;
                float px = xc[j] + (float)(w0 + j), py = yc[j] + (float)h_i;
                px0[j] = px - 0.5f * pw; py0[j] = py - 0.5f * ph;
                px1[j] = px + 0.5f * pw; py1[j] = py + 0.5f * ph;
                ap[j] = pw * ph;
                miou[j] = 0.f;
            }
            // g outer, cells inner: LDS values loaded once per g
            #pragma unroll
            for (int g = 0; g < G; ++g) {
                float gx0 = s_x0[g], gy0 = s_y0[g];
                float gx1 = s_x1[g], gy1 = s_y1[g], ag = s_ag[g];
                #pragma unroll
                for (int j = 0; j < 4; ++j) {
                    float iw = fmaxf(fminf(px1[j], gx1) - fmaxf(px0[j], gx0), 0.f);
                    float ih = fmaxf(fminf(py1[j], gy1) - fmaxf(py0[j], gy0), 0.f);
                    float inter = iw * ih;
                    float iou = inter * rcp_(ap[j] + ag - inter + 1e-10f);
                    miou[j] = fmaxf(miou[j], iou);
                }
            }
            #pragma unroll
            for (int j = 0; j < 4; ++j) {
                bool ignore = miou[j] > 0.5f;
                sc += (ignore ? 0.0f : 0.5f) * softplusf_(o4[j]);
                if (wu) {
                    sx += (xc[j] - 0.5f) * (xc[j] - 0.5f);
                    sy += (yc[j] - 0.5f) * (yc[j] - 0.5f);
                    sw += o2[j] * o2[j];
                    sh += o3[j] * o3[j];
                }
            }
        }
        #pragma unroll
        for (int off = 32; off > 0; off >>= 1) {
            sc += __shfl_down(sc, off);
            sx += __shfl_down(sx, off);
            sy += __shfl_down(sy, off);
            sw += __shfl_down(sw, off);
            sh += __shfl_down(sh, off);
        }
        if (lane == 0) {
            red[wid][0] = sc; red[wid][1] = sx; red[wid][2] = sy;
            red[wid][3] = sw; red[wid][4] = sh;
        }
        __syncthreads();
        if (t == 0) {
            float r0 = 0.f, r1 = 0.f, r2 = 0.f, r3 = 0.f, r4 = 0.f;
            #pragma unroll
            for (int w = 0; w < 4; ++w) {
                r0 += red[w][0]; r1 += red[w][1]; r2 += red[w][2];
                r3 += red[w][3]; r4 += red[w][4];
            }
            float4* dst = (float4*)(ws + (size_t)bid * 8);
            dst[0] = make_float4(r0, r1, r2, r3);
            dst[1] = make_float4(r4, 0.f, 0.f, 0.f);
        }
    } else {
        // ================= pair path: one wave per (b,g) pair =================
        int pb = bid - CELL_BLOCKS;
        int p = pb * 4 + wid;            // < 640 always
        int b = p / G, g = p % G;

        const float* gb = bboxes + (size_t)b * G * 4;
        float gx = gb[g*4+0] * 0.125f, gy = gb[g*4+1] * 0.125f;
        float gw = gb[g*4+2] * 0.125f, gh = gb[g*4+3] * 0.125f;
        int a = anchor_idx[p];
        int gi = min(max((int)gx, 0), NW - 1);
        int gj = min(max((int)gy, 0), NH - 1);

        const float* cell = out + ((size_t)b * NA * CH + (size_t)a * CH) * PLANE
                                + gj * NW + gi;

        // class BCE loads in lane-parallel (issue early)
        int lab = labels[p];
        float v1 = cell[(size_t)(5 + lane) * PLANE];
        float v2 = (lane < NC - 64) ? cell[(size_t)(5 + 64 + lane) * PLANE] : 0.f;
        float s = softplusf_(v1) - ((lane == lab) ? v1 : 0.f);
        if (lane < NC - 64)
            s += softplusf_(v2) - (((64 + lane) == lab) ? v2 : 0.f);

        float o0 = cell[0];
        float o1 = cell[PLANE];
        float o2 = cell[2 * PLANE];
        float o3 = cell[3 * PLANE];
        float o4 = cell[4 * PLANE];

        float xc = sigmoidf_(o0), yc = sigmoidf_(o1);
        float pw = __expf(o2) * c_aw[a];
        float ph = __expf(o3) * c_ah[a];
        float px = xc + (float)gi, py = yc + (float)gj;
        float px0 = px - 0.5f*pw, py0 = py - 0.5f*ph;
        float px1 = px + 0.5f*pw, py1 = py + 0.5f*ph;
        float ap = pw * ph;

        // nCorrect: all pairs, no dedupe
        float ncorr;
        {
            float gx0 = gx - 0.5f*gw, gy0 = gy - 0.5f*gh;
            float gx1 = gx + 0.5f*gw, gy1 = gy + 0.5f*gh;
            float ag = gw * gh;
            float iw = fmaxf(fminf(px1, gx1) - fmaxf(px0, gx0), 0.f);
            float ih = fmaxf(fminf(py1, gy1) - fmaxf(py0, gy0), 0.f);
            float inter = iw * ih;
            float iou = inter * rcp_(ap + ag - inter + 1e-10f);
            ncorr = (iou > 0.5f) ? 1.0f : 0.0f;
        }

        // last-wins dedupe (wave-uniform; no early return — block sync below)
        bool active = true;
        for (int q = g + 1; q < G; ++q) {
            int aq = anchor_idx[b * G + q];
            if (aq != a) continue;
            float qx = gb[q*4+0] * 0.125f, qy = gb[q*4+1] * 0.125f;
            int qi = min(max((int)qx, 0), NW - 1);
            int qj = min(max((int)qy, 0), NH - 1);
            if (qi == gi && qj == gj) { active = false; break; }
        }

        bool ignore = false;
        if (active) {
            float miou = 0.f;
            for (int q = 0; q < G; ++q) {
                float qx = gb[q*4+0] * 0.125f, qy = gb[q*4+1] * 0.125f;
                float qw = gb[q*4+2] * 0.125f, qh = gb[q*4+3] * 0.125f;
                float qx0 = qx - 0.5f*qw, qy0 = qy - 0.5f*qh;
                float qx1 = qx + 0.5f*qw, qy1 = qy + 0.5f*qh;
                float ag = qw * qh;
                float iw = fmaxf(fminf(px1, qx1) - fmaxf(px0, qx0), 0.f);
                float ih = fmaxf(fminf(py1, qy1) - fmaxf(py0, qy0), 0.f);
                float inter = iw * ih;
                float iou = inter * rcp_(ap + ag - inter + 1e-10f);
                miou = fmaxf(miou, iou);
            }
            ignore = miou > 0.5f;
        }

        // reduce class sum across the wave
        #pragma unroll
        for (int off = 32; off > 0; off >>= 1) s += __shfl_down(s, off);

        if (lane == 0) {
            float dconf = 0.f, dxc = 0.f, dyc = 0.f, dw = 0.f, dh = 0.f, dcls = 0.f;
            if (active) {
                float sp4 = softplusf_(o4);
                float base_conf = (ignore ? 0.0f : 0.5f) * sp4;
                dconf = 5.0f * (sp4 - o4) - base_conf;

                float txc = gx - (float)gi;
                float tyc = gy - (float)gj;
                float tw  = __logf(gw / c_aw[a]);
                float th  = __logf(gh / c_ah[a]);
                bool wu = (*warm_up != 0);
                float bx = wu ? (xc - 0.5f) * (xc - 0.5f) : 0.f;
                float by = wu ? (yc - 0.5f) * (yc - 0.5f) : 0.f;
                float bw = wu ? o2 * o2 : 0.f;
                float bh = wu ? o3 * o3 : 0.f;
                dxc = (xc - txc) * (xc - txc) - bx;
                dyc = (yc - tyc) * (yc - tyc) - by;
                dw  = (o2 - tw) * (o2 - tw) - bw;
                dh  = (o3 - th) * (o3 - th) - bh;
                dcls = s;
            }
            red[wid][0] = dconf; red[wid][1] = dxc; red[wid][2] = dyc;
            red[wid][3] = dw;    red[wid][4] = dh;  red[wid][5] = dcls;
            red[wid][6] = ncorr;
        }
        __syncthreads();
        if (t == 0) {
            float r[7];
            #pragma unroll
            for (int k = 0; k < 7; ++k)
                r[k] = red[0][k] + red[1][k] + red[2][k] + red[3][k];
            float4* dst = (float4*)(ws + (size_t)bid * 8);
            dst[0] = make_float4(r[0], r[1], r[2], r[3]);
            dst[1] = make_float4(r[4], r[5], r[6], 0.f);
        }
    }
}

__global__ void __launch_bounds__(256)
finalize_kernel(const float* __restrict__ ws, float* __restrict__ o)
{
    __shared__ float red[4][7];
    int t = threadIdx.x;
    float a0=0,a1=0,a2=0,a3=0,a4=0,a5=0,a6=0;

    {
        const float4* r = (const float4*)(ws + (size_t)t * 8);
        float4 lo = r[0], hi = r[1];
        a0 += lo.x; a1 += lo.y; a2 += lo.z; a3 += lo.w;
        a4 += hi.x; a5 += hi.y; a6 += hi.z;
    }
    if (t < TOTAL_ROWS - 256) {
        const float4* r = (const float4*)(ws + (size_t)(256 + t) * 8);
        float4 lo = r[0], hi = r[1];
        a0 += lo.x; a1 += lo.y; a2 += lo.z; a3 += lo.w;
        a4 += hi.x; a5 += hi.y; a6 += hi.z;
    }
    #pragma unroll
    for (int off = 32; off > 0; off >>= 1) {
        a0 += __shfl_down(a0, off);
        a1 += __shfl_down(a1, off);
        a2 += __shfl_down(a2, off);
        a3 += __shfl_down(a3, off);
        a4 += __shfl_down(a4, off);
        a5 += __shfl_down(a5, off);
        a6 += __shfl_down(a6, off);
    }
    int lane = t & 63, wid = t >> 6;
    if (lane == 0) {
        red[wid][0]=a0; red[wid][1]=a1; red[wid][2]=a2; red[wid][3]=a3;
        red[wid][4]=a4; red[wid][5]=a5; red[wid][6]=a6;
    }
    __syncthreads();
    if (t == 0) {
        float c0=0,c1=0,c2=0,c3=0,c4=0,c5=0,c6=0;
        #pragma unroll
        for (int w = 0; w < 4; ++w) {
            c0+=red[w][0]; c1+=red[w][1]; c2+=red[w][2]; c3+=red[w][3];
            c4+=red[w][4]; c5+=red[w][5]; c6+=red[w][6];
        }
        const float invB = 1.0f / (float)NB;
        float lxc = c1 * 0.5f * invB;
        float lyc = c2 * 0.5f * invB;
        float lw  = c3 * 0.5f * invB;
        float lh  = c4 * 0.5f * invB;
        float lconf = c0 * invB;
        float lcls  = c5 * invB;
        o[0] = lxc + lyc + lw + lh + lconf + lcls;
        o[1] = (float)(NB * G);   // nGT
        o[2] = c6;                // nCorrect
        o[3] = lxc;
        o[4] = lyc;
        o[5] = lw;
        o[6] = lh;
        o[7] = lconf;
        o[8] = lcls;
    }
}

extern "C" void kernel_launch(void* const* d_in, const int* in_sizes, int n_in,
                              void* d_out, int out_size, void* d_ws, size_t ws_size,
                              hipStream_t stream)
{
    const float* output     = (const float*)d_in[0];
    const float* bboxes     = (const float*)d_in[1];
    const int*   labels     = (const int*)d_in[2];
    const int*   anchor_idx = (const int*)d_in[3];
    const int*   warm_up    = (const int*)d_in[4];
    float* ws   = (float*)d_ws;
    float* outp = (float*)d_out;

    main_kernel<<<CELL_BLOCKS + PAIR_BLOCKS, 256, 0, stream>>>(
        output, bboxes, labels, anchor_idx, warm_up, ws);
    finalize_kernel<<<1, 256, 0, stream>>>(ws, outp);
}